// Round 1
// baseline (228.796 us; speedup 1.0000x reference)
//
#include <hip/hip_runtime.h>
#include <hip/hip_bf16.h>

#define B_ 32
#define N_ 512
#define H_ 128

typedef float f32x4 __attribute__((ext_vector_type(4)));
typedef short short8 __attribute__((ext_vector_type(8)));
typedef short short4v __attribute__((ext_vector_type(4)));

static __device__ __forceinline__ float bf2f(unsigned short u) {
  union { unsigned int ui; float f; } x;
  x.ui = ((unsigned int)u) << 16;
  return x.f;
}
static __device__ __forceinline__ unsigned short f2bf(float f) {
  __hip_bfloat16 h = __float2bfloat16(f);
  return *reinterpret_cast<unsigned short*>(&h);
}

// -------------------------------------------------------------------------
// Kernel 1: h[b,n,d] = silu(LN(s[b,n,:] @ W1[d,:] + b1[d]))
// stored TRANSPOSED bf16 into ws:  h_t[b][d][n]  (n contiguous, k-major for
// the MFMA B-operand of kernel 2).
// Grid: (N/32, B), block 256. Tile: 32 n-rows x 128 d.
// Thread (a = t&15, g = t>>4): owns d = dd*16+a (dd<8), n = nn*16+g (nn<2).
// (unchanged from previous round — not the bottleneck per rocprof)
// -------------------------------------------------------------------------
__global__ __launch_bounds__(256) void lin_ln_silu_kernel(
    const float* __restrict__ s, const float* __restrict__ W1,
    const float* __restrict__ b1, unsigned short* __restrict__ h_t) {
  __shared__ float s_sh[32 * 132];            // [n][k] fp32, pad 132
  __shared__ unsigned short w_sh[128 * 132];  // [d][k] bf16, pad 132
  __shared__ unsigned short ht_sh[128 * 40];  // [d][n] bf16, pad 40
  const int t = threadIdx.x;
  const int b = blockIdx.y;
  const int n0 = blockIdx.x * 32;

  // stage W1 (128x128) fp32 -> bf16 LDS, coalesced float4 reads
#pragma unroll
  for (int r = 0; r < 16; ++r) {
    int q = t + 256 * r;
    int d = q >> 5, part = q & 31;
    float4 v = *reinterpret_cast<const float4*>(W1 + d * H_ + part * 4);
    short4v w;
    w.x = (short)f2bf(v.x); w.y = (short)f2bf(v.y);
    w.z = (short)f2bf(v.z); w.w = (short)f2bf(v.w);
    *reinterpret_cast<short4v*>(&w_sh[d * 132 + part * 4]) = w;
  }
  // stage s tile (32x128 fp32)
#pragma unroll
  for (int r = 0; r < 4; ++r) {
    int q = t + 256 * r;
    int n = q >> 5, part = q & 31;
    float4 v = *reinterpret_cast<const float4*>(
        s + ((size_t)b * N_ + n0 + n) * H_ + part * 4);
    *reinterpret_cast<float4*>(&s_sh[n * 132 + part * 4]) = v;
  }
  __syncthreads();

  const int a = t & 15;
  const int g = t >> 4;
  float acc[2][8];
#pragma unroll
  for (int nn = 0; nn < 2; ++nn)
#pragma unroll
    for (int dd = 0; dd < 8; ++dd) acc[nn][dd] = 0.f;

  float bias[8];
#pragma unroll
  for (int dd = 0; dd < 8; ++dd) bias[dd] = b1[dd * 16 + a];

  for (int k = 0; k < 128; k += 4) {
    float wf[8][4];
#pragma unroll
    for (int dd = 0; dd < 8; ++dd) {
      short4v wv =
          *reinterpret_cast<const short4v*>(&w_sh[(dd * 16 + a) * 132 + k]);
      wf[dd][0] = bf2f((unsigned short)wv.x);
      wf[dd][1] = bf2f((unsigned short)wv.y);
      wf[dd][2] = bf2f((unsigned short)wv.z);
      wf[dd][3] = bf2f((unsigned short)wv.w);
    }
#pragma unroll
    for (int nn = 0; nn < 2; ++nn) {
      float4 sv =
          *reinterpret_cast<const float4*>(&s_sh[(nn * 16 + g) * 132 + k]);
#pragma unroll
      for (int dd = 0; dd < 8; ++dd) {
        acc[nn][dd] += sv.x * wf[dd][0] + sv.y * wf[dd][1] +
                       sv.z * wf[dd][2] + sv.w * wf[dd][3];
      }
    }
  }

  // bias + LayerNorm over d (128) per n-row (16 lanes x 8 d each) + SiLU
#pragma unroll
  for (int nn = 0; nn < 2; ++nn) {
    float s1 = 0.f, s2 = 0.f;
#pragma unroll
    for (int dd = 0; dd < 8; ++dd) {
      float x = acc[nn][dd] + bias[dd];
      acc[nn][dd] = x;
      s1 += x;
      s2 += x * x;
    }
#pragma unroll
    for (int off = 8; off >= 1; off >>= 1) {
      s1 += __shfl_xor(s1, off);
      s2 += __shfl_xor(s2, off);
    }
    float mean = s1 * (1.f / 128.f);
    float var = s2 * (1.f / 128.f) - mean * mean;
    float rs = rsqrtf(var + 1e-5f);
#pragma unroll
    for (int dd = 0; dd < 8; ++dd) {
      float x = (acc[nn][dd] - mean) * rs;
      float y = x / (1.f + __expf(-x));  // silu
      ht_sh[(dd * 16 + a) * 40 + nn * 16 + g] = f2bf(y);
    }
  }
  __syncthreads();

  // coalesced copy-out: 128 d-rows x 32 n (64 B/row)
#pragma unroll
  for (int r = 0; r < 2; ++r) {
    int q = t + 256 * r;
    int d = q >> 2, part = q & 3;
    float4 v = *reinterpret_cast<const float4*>(&ht_sh[d * 40 + part * 8]);
    *reinterpret_cast<float4*>(
        h_t + ((size_t)b * 128 + d) * 512 + n0 + part * 8) = v;
  }
}

// -------------------------------------------------------------------------
// Kernel 2: v[b,i,c,d] = sum_j mask[b,i,j]*ev[b,i,j,c]*h[b,j,d]  via MFMA.
// Per block: b, 16 i's. M-tile = 48 (m = c*16+il), N = 128 (d), K = 512 (j).
// NEW this round (T14 async-STAGE + lgkm-only barriers):
//  - round r+1's global loads (h_t 4xfloat4, ev 3xfloat4, mask 1xfloat4)
//    are issued into registers BEFORE round r's MFMAs; barriers wait only
//    lgkmcnt, so the loads stay in flight across both barriers and are
//    drained only where the next round's LDS-write consumes them.
//  - ph staging: thread <-> (i, j-group-of-4): contiguous 48B ev + 16B mask,
//    compile-time unpack (no div/mod, no scalar mask loads), 3x ds_write_b64.
// Grid: (N/16, B), block 256 (4 waves; wave w covers d in [w*32, w*32+32)).
// -------------------------------------------------------------------------
__global__ __launch_bounds__(256) void cfconv_mfma_kernel(
    const float* __restrict__ ev, const float* __restrict__ mask,
    const unsigned short* __restrict__ h_t, float* __restrict__ out) {
  __shared__ unsigned short ph[48 * 72];   // [m=c*16+il][j] bf16, pad 72
  __shared__ unsigned short hh[128 * 72];  // [d][j] bf16, pad 72
  const int t = threadIdx.x;
  const int b = blockIdx.y;
  const int i0 = blockIdx.x * 16;
  const int lane = t & 63;
  const int w = t >> 6;
  const int l15 = lane & 15;
  const int quad = lane >> 4;

  // staging roles: ph loader owns (i = si, j in [4*sj, 4*sj+4) of each round)
  const int si = t >> 4;  // 0..15
  const int sj = t & 15;  // 0..15
  const float* evbase =
      ev + ((size_t)(b * N_ + i0 + si)) * N_ * 3 + (size_t)sj * 12;
  const float* mbase = mask + ((size_t)(b * N_ + i0 + si)) * N_ + sj * 4;

  f32x4 acc[3][2];
#pragma unroll
  for (int mt = 0; mt < 3; ++mt)
#pragma unroll
    for (int nt = 0; nt < 2; ++nt)
#pragma unroll
      for (int e = 0; e < 4; ++e) acc[mt][nt][e] = 0.f;

  // prefetch registers (round r+1 data lives here while round r computes)
  float4 hv[4];
  float4 evv[3];
  float4 mkv;

  // ---- prologue: issue round-0 loads
#pragma unroll
  for (int r2 = 0; r2 < 4; ++r2) {
    int q = t + 256 * r2;
    int d = q >> 3, p8 = q & 7;
    hv[r2] = *reinterpret_cast<const float4*>(
        h_t + ((size_t)b * 128 + d) * 512 + p8 * 8);
  }
#pragma unroll
  for (int e = 0; e < 3; ++e)
    evv[e] = *reinterpret_cast<const float4*>(evbase + e * 4);
  mkv = *reinterpret_cast<const float4*>(mbase);

  for (int r = 0; r < 8; ++r) {
    // ---- sync1: previous round's LDS readers done before overwrite.
    // lgkm-only wait: in-flight global loads are NOT drained here.
    asm volatile("s_waitcnt lgkmcnt(0)" ::: "memory");
    __builtin_amdgcn_s_barrier();

    // ---- write LDS from prefetched regs (compiler inserts the vmcnt
    // waits right before first use — loads had a full round to fly)
#pragma unroll
    for (int r2 = 0; r2 < 4; ++r2) {
      int q = t + 256 * r2;
      int d = q >> 3, p8 = q & 7;
      *reinterpret_cast<float4*>(&hh[d * 72 + p8 * 8]) = hv[r2];
    }
    {
      // 12 contiguous ev floats = (jj=0..3) x (c=0..2), f = jj*3 + c
      float f[12] = {evv[0].x, evv[0].y, evv[0].z, evv[0].w,
                     evv[1].x, evv[1].y, evv[1].z, evv[1].w,
                     evv[2].x, evv[2].y, evv[2].z, evv[2].w};
      float mk[4] = {mkv.x, mkv.y, mkv.z, mkv.w};
#pragma unroll
      for (int c = 0; c < 3; ++c) {
        short4v pk;
        pk.x = (short)f2bf(f[0 * 3 + c] * mk[0]);
        pk.y = (short)f2bf(f[1 * 3 + c] * mk[1]);
        pk.z = (short)f2bf(f[2 * 3 + c] * mk[2]);
        pk.w = (short)f2bf(f[3 * 3 + c] * mk[3]);
        *reinterpret_cast<short4v*>(&ph[(c * 16 + si) * 72 + sj * 4]) = pk;
      }
    }

    // ---- sync2: this wave's ds_writes committed, then barrier
    asm volatile("s_waitcnt lgkmcnt(0)" ::: "memory");
    __builtin_amdgcn_s_barrier();

    // ---- issue round r+1 global loads (stay in flight across the MFMAs
    // and across next round's sync1 — lgkm-only barriers don't drain vmcnt)
    if (r < 7) {
      const int jn = (r + 1) * 64;
#pragma unroll
      for (int r2 = 0; r2 < 4; ++r2) {
        int q = t + 256 * r2;
        int d = q >> 3, p8 = q & 7;
        hv[r2] = *reinterpret_cast<const float4*>(
            h_t + ((size_t)b * 128 + d) * 512 + jn + p8 * 8);
      }
#pragma unroll
      for (int e = 0; e < 3; ++e)
        evv[e] = *reinterpret_cast<const float4*>(evbase + (size_t)jn * 3 + e * 4);
      mkv = *reinterpret_cast<const float4*>(mbase + jn);
    }

    // ---- compute: 2 k-slabs of 32
#pragma unroll
    for (int ks = 0; ks < 2; ++ks) {
      short8 av[3], bv[2];
#pragma unroll
      for (int mt = 0; mt < 3; ++mt)
        av[mt] = *reinterpret_cast<const short8*>(
            &ph[(mt * 16 + l15) * 72 + ks * 32 + quad * 8]);
#pragma unroll
      for (int nt = 0; nt < 2; ++nt) {
        int d = w * 32 + nt * 16 + l15;
        bv[nt] = *reinterpret_cast<const short8*>(
            &hh[d * 72 + ks * 32 + quad * 8]);
      }
#pragma unroll
      for (int mt = 0; mt < 3; ++mt)
#pragma unroll
        for (int nt = 0; nt < 2; ++nt)
          acc[mt][nt] = __builtin_amdgcn_mfma_f32_16x16x32_bf16(
              av[mt], bv[nt], acc[mt][nt], 0, 0, 0);
    }
  }

  // epilogue: C/D layout col=lane&15 (d), row=quad*4+reg (il); c = mt
#pragma unroll
  for (int mt = 0; mt < 3; ++mt) {
#pragma unroll
    for (int nt = 0; nt < 2; ++nt) {
      int d = w * 32 + nt * 16 + l15;
#pragma unroll
      for (int r = 0; r < 4; ++r) {
        int i = i0 + quad * 4 + r;
        out[(((size_t)b * N_ + i) * 3 + mt) * H_ + d] = acc[mt][nt][r];
      }
    }
  }
}

extern "C" void kernel_launch(void* const* d_in, const int* in_sizes, int n_in,
                              void* d_out, int out_size, void* d_ws,
                              size_t ws_size, hipStream_t stream) {
  const float* s = (const float*)d_in[0];
  const float* ev = (const float*)d_in[1];
  const float* mask = (const float*)d_in[2];
  const float* W1 = (const float*)d_in[3];
  const float* b1 = (const float*)d_in[4];
  float* out = (float*)d_out;
  // ws: h_t bf16 [B][128 d][512 n] = 4 MB
  unsigned short* h_t = (unsigned short*)d_ws;

  lin_ln_silu_kernel<<<dim3(N_ / 32, B_), 256, 0, stream>>>(s, W1, b1, h_t);
  cfconv_mfma_kernel<<<dim3(N_ / 16, B_), 256, 0, stream>>>(ev, mask, h_t, out);
}

// Round 2
// 212.422 us; speedup vs baseline: 1.0771x; 1.0771x over previous
//
#include <hip/hip_runtime.h>
#include <hip/hip_bf16.h>

#define B_ 32
#define N_ 512
#define H_ 128

typedef float f32x4 __attribute__((ext_vector_type(4)));
typedef short short8 __attribute__((ext_vector_type(8)));
typedef short short4v __attribute__((ext_vector_type(4)));

static __device__ __forceinline__ float bf2f(unsigned short u) {
  union { unsigned int ui; float f; } x;
  x.ui = ((unsigned int)u) << 16;
  return x.f;
}
static __device__ __forceinline__ unsigned short f2bf(float f) {
  __hip_bfloat16 h = __float2bfloat16(f);
  return *reinterpret_cast<unsigned short*>(&h);
}

// -------------------------------------------------------------------------
// Kernel 1: h[b,n,d] = silu(LN(s[b,n,:] @ W1[d,:] + b1[d]))
// stored TRANSPOSED bf16 into ws:  h_t[b][d][n]  (n contiguous, k-major for
// the MFMA B-operand of kernel 2).
// Grid: (N/32, B), block 256. Tile: 32 n-rows x 128 d.
// (unchanged — not the bottleneck per rocprof)
// -------------------------------------------------------------------------
__global__ __launch_bounds__(256) void lin_ln_silu_kernel(
    const float* __restrict__ s, const float* __restrict__ W1,
    const float* __restrict__ b1, unsigned short* __restrict__ h_t) {
  __shared__ float s_sh[32 * 132];            // [n][k] fp32, pad 132
  __shared__ unsigned short w_sh[128 * 132];  // [d][k] bf16, pad 132
  __shared__ unsigned short ht_sh[128 * 40];  // [d][n] bf16, pad 40
  const int t = threadIdx.x;
  const int b = blockIdx.y;
  const int n0 = blockIdx.x * 32;

  // stage W1 (128x128) fp32 -> bf16 LDS, coalesced float4 reads
#pragma unroll
  for (int r = 0; r < 16; ++r) {
    int q = t + 256 * r;
    int d = q >> 5, part = q & 31;
    float4 v = *reinterpret_cast<const float4*>(W1 + d * H_ + part * 4);
    short4v w;
    w.x = (short)f2bf(v.x); w.y = (short)f2bf(v.y);
    w.z = (short)f2bf(v.z); w.w = (short)f2bf(v.w);
    *reinterpret_cast<short4v*>(&w_sh[d * 132 + part * 4]) = w;
  }
  // stage s tile (32x128 fp32)
#pragma unroll
  for (int r = 0; r < 4; ++r) {
    int q = t + 256 * r;
    int n = q >> 5, part = q & 31;
    float4 v = *reinterpret_cast<const float4*>(
        s + ((size_t)b * N_ + n0 + n) * H_ + part * 4);
    *reinterpret_cast<float4*>(&s_sh[n * 132 + part * 4]) = v;
  }
  __syncthreads();

  const int a = t & 15;
  const int g = t >> 4;
  float acc[2][8];
#pragma unroll
  for (int nn = 0; nn < 2; ++nn)
#pragma unroll
    for (int dd = 0; dd < 8; ++dd) acc[nn][dd] = 0.f;

  float bias[8];
#pragma unroll
  for (int dd = 0; dd < 8; ++dd) bias[dd] = b1[dd * 16 + a];

  for (int k = 0; k < 128; k += 4) {
    float wf[8][4];
#pragma unroll
    for (int dd = 0; dd < 8; ++dd) {
      short4v wv =
          *reinterpret_cast<const short4v*>(&w_sh[(dd * 16 + a) * 132 + k]);
      wf[dd][0] = bf2f((unsigned short)wv.x);
      wf[dd][1] = bf2f((unsigned short)wv.y);
      wf[dd][2] = bf2f((unsigned short)wv.z);
      wf[dd][3] = bf2f((unsigned short)wv.w);
    }
#pragma unroll
    for (int nn = 0; nn < 2; ++nn) {
      float4 sv =
          *reinterpret_cast<const float4*>(&s_sh[(nn * 16 + g) * 132 + k]);
#pragma unroll
      for (int dd = 0; dd < 8; ++dd) {
        acc[nn][dd] += sv.x * wf[dd][0] + sv.y * wf[dd][1] +
                       sv.z * wf[dd][2] + sv.w * wf[dd][3];
      }
    }
  }

  // bias + LayerNorm over d (128) per n-row (16 lanes x 8 d each) + SiLU
#pragma unroll
  for (int nn = 0; nn < 2; ++nn) {
    float s1 = 0.f, s2 = 0.f;
#pragma unroll
    for (int dd = 0; dd < 8; ++dd) {
      float x = acc[nn][dd] + bias[dd];
      acc[nn][dd] = x;
      s1 += x;
      s2 += x * x;
    }
#pragma unroll
    for (int off = 8; off >= 1; off >>= 1) {
      s1 += __shfl_xor(s1, off);
      s2 += __shfl_xor(s2, off);
    }
    float mean = s1 * (1.f / 128.f);
    float var = s2 * (1.f / 128.f) - mean * mean;
    float rs = rsqrtf(var + 1e-5f);
#pragma unroll
    for (int dd = 0; dd < 8; ++dd) {
      float x = (acc[nn][dd] - mean) * rs;
      float y = x / (1.f + __expf(-x));  // silu
      ht_sh[(dd * 16 + a) * 40 + nn * 16 + g] = f2bf(y);
    }
  }
  __syncthreads();

  // coalesced copy-out: 128 d-rows x 32 n (64 B/row)
#pragma unroll
  for (int r = 0; r < 2; ++r) {
    int q = t + 256 * r;
    int d = q >> 2, part = q & 3;
    float4 v = *reinterpret_cast<const float4*>(&ht_sh[d * 40 + part * 8]);
    *reinterpret_cast<float4*>(
        h_t + ((size_t)b * 128 + d) * 512 + n0 + part * 8) = v;
  }
}

// -------------------------------------------------------------------------
// Kernel 2: v[b,i,c,d] = sum_j mask[b,i,j]*ev[b,i,j,c]*h[b,j,d]  via MFMA.
// Per block: b, 16 i's. M-tile = 48 (m = c*16+il), N = 128 (d), K = 512 (j).
// T14 async-STAGE + lgkm-only barriers (round 1), PLUS this round:
//   __launch_bounds__(256, 4): min 4 waves/EU = 4 blocks/CU (all the 1024-
//   block grid can resident anyway) -> VGPR cap 128 instead of the default
//   heuristic's 64. Round 1 spilled the 32 prefetch regs to scratch
//   (WRITE_SIZE 24.6MB->123MB, VGPR_Count 52); this gives them registers.
// Grid: (N/16, B), block 256 (4 waves; wave w covers d in [w*32, w*32+32)).
// -------------------------------------------------------------------------
__global__ __launch_bounds__(256, 4) void cfconv_mfma_kernel(
    const float* __restrict__ ev, const float* __restrict__ mask,
    const unsigned short* __restrict__ h_t, float* __restrict__ out) {
  __shared__ unsigned short ph[48 * 72];   // [m=c*16+il][j] bf16, pad 72
  __shared__ unsigned short hh[128 * 72];  // [d][j] bf16, pad 72
  const int t = threadIdx.x;
  const int b = blockIdx.y;
  const int i0 = blockIdx.x * 16;
  const int lane = t & 63;
  const int w = t >> 6;
  const int l15 = lane & 15;
  const int quad = lane >> 4;

  // staging roles: ph loader owns (i = si, j in [4*sj, 4*sj+4) of each round)
  const int si = t >> 4;  // 0..15
  const int sj = t & 15;  // 0..15
  const float* evbase =
      ev + ((size_t)(b * N_ + i0 + si)) * N_ * 3 + (size_t)sj * 12;
  const float* mbase = mask + ((size_t)(b * N_ + i0 + si)) * N_ + sj * 4;

  f32x4 acc[3][2];
#pragma unroll
  for (int mt = 0; mt < 3; ++mt)
#pragma unroll
    for (int nt = 0; nt < 2; ++nt)
#pragma unroll
      for (int e = 0; e < 4; ++e) acc[mt][nt][e] = 0.f;

  // prefetch registers (round r+1 data lives here while round r computes)
  float4 hv[4];
  float4 evv[3];
  float4 mkv;

  // ---- prologue: issue round-0 loads
#pragma unroll
  for (int r2 = 0; r2 < 4; ++r2) {
    int q = t + 256 * r2;
    int d = q >> 3, p8 = q & 7;
    hv[r2] = *reinterpret_cast<const float4*>(
        h_t + ((size_t)b * 128 + d) * 512 + p8 * 8);
  }
#pragma unroll
  for (int e = 0; e < 3; ++e)
    evv[e] = *reinterpret_cast<const float4*>(evbase + e * 4);
  mkv = *reinterpret_cast<const float4*>(mbase);

  for (int r = 0; r < 8; ++r) {
    // ---- sync1: previous round's LDS readers done before overwrite.
    // lgkm-only wait: in-flight global loads are NOT drained here.
    asm volatile("s_waitcnt lgkmcnt(0)" ::: "memory");
    __builtin_amdgcn_s_barrier();

    // ---- write LDS from prefetched regs (compiler inserts the vmcnt
    // waits right before first use — loads had a full round to fly)
#pragma unroll
    for (int r2 = 0; r2 < 4; ++r2) {
      int q = t + 256 * r2;
      int d = q >> 3, p8 = q & 7;
      *reinterpret_cast<float4*>(&hh[d * 72 + p8 * 8]) = hv[r2];
    }
    {
      // 12 contiguous ev floats = (jj=0..3) x (c=0..2), f = jj*3 + c
      float f[12] = {evv[0].x, evv[0].y, evv[0].z, evv[0].w,
                     evv[1].x, evv[1].y, evv[1].z, evv[1].w,
                     evv[2].x, evv[2].y, evv[2].z, evv[2].w};
      float mk[4] = {mkv.x, mkv.y, mkv.z, mkv.w};
#pragma unroll
      for (int c = 0; c < 3; ++c) {
        short4v pk;
        pk.x = (short)f2bf(f[0 * 3 + c] * mk[0]);
        pk.y = (short)f2bf(f[1 * 3 + c] * mk[1]);
        pk.z = (short)f2bf(f[2 * 3 + c] * mk[2]);
        pk.w = (short)f2bf(f[3 * 3 + c] * mk[3]);
        *reinterpret_cast<short4v*>(&ph[(c * 16 + si) * 72 + sj * 4]) = pk;
      }
    }

    // ---- sync2: this wave's ds_writes committed, then barrier
    asm volatile("s_waitcnt lgkmcnt(0)" ::: "memory");
    __builtin_amdgcn_s_barrier();

    // ---- issue round r+1 global loads (stay in flight across the MFMAs
    // and across next round's sync1 — lgkm-only barriers don't drain vmcnt)
    if (r < 7) {
      const int jn = (r + 1) * 64;
#pragma unroll
      for (int r2 = 0; r2 < 4; ++r2) {
        int q = t + 256 * r2;
        int d = q >> 3, p8 = q & 7;
        hv[r2] = *reinterpret_cast<const float4*>(
            h_t + ((size_t)b * 128 + d) * 512 + jn + p8 * 8);
      }
#pragma unroll
      for (int e = 0; e < 3; ++e)
        evv[e] = *reinterpret_cast<const float4*>(evbase + (size_t)jn * 3 + e * 4);
      mkv = *reinterpret_cast<const float4*>(mbase + jn);
    }

    // ---- compute: 2 k-slabs of 32
#pragma unroll
    for (int ks = 0; ks < 2; ++ks) {
      short8 av[3], bv[2];
#pragma unroll
      for (int mt = 0; mt < 3; ++mt)
        av[mt] = *reinterpret_cast<const short8*>(
            &ph[(mt * 16 + l15) * 72 + ks * 32 + quad * 8]);
#pragma unroll
      for (int nt = 0; nt < 2; ++nt) {
        int d = w * 32 + nt * 16 + l15;
        bv[nt] = *reinterpret_cast<const short8*>(
            &hh[d * 72 + ks * 32 + quad * 8]);
      }
#pragma unroll
      for (int mt = 0; mt < 3; ++mt)
#pragma unroll
        for (int nt = 0; nt < 2; ++nt)
          acc[mt][nt] = __builtin_amdgcn_mfma_f32_16x16x32_bf16(
              av[mt], bv[nt], acc[mt][nt], 0, 0, 0);
    }
  }

  // epilogue: C/D layout col=lane&15 (d), row=quad*4+reg (il); c = mt
#pragma unroll
  for (int mt = 0; mt < 3; ++mt) {
#pragma unroll
    for (int nt = 0; nt < 2; ++nt) {
      int d = w * 32 + nt * 16 + l15;
#pragma unroll
      for (int r = 0; r < 4; ++r) {
        int i = i0 + quad * 4 + r;
        out[(((size_t)b * N_ + i) * 3 + mt) * H_ + d] = acc[mt][nt][r];
      }
    }
  }
}

extern "C" void kernel_launch(void* const* d_in, const int* in_sizes, int n_in,
                              void* d_out, int out_size, void* d_ws,
                              size_t ws_size, hipStream_t stream) {
  const float* s = (const float*)d_in[0];
  const float* ev = (const float*)d_in[1];
  const float* mask = (const float*)d_in[2];
  const float* W1 = (const float*)d_in[3];
  const float* b1 = (const float*)d_in[4];
  float* out = (float*)d_out;
  // ws: h_t bf16 [B][128 d][512 n] = 4 MB
  unsigned short* h_t = (unsigned short*)d_ws;

  lin_ln_silu_kernel<<<dim3(N_ / 32, B_), 256, 0, stream>>>(s, W1, b1, h_t);
  cfconv_mfma_kernel<<<dim3(N_ / 16, B_), 256, 0, stream>>>(ev, mask, h_t, out);
}

// Round 3
// 212.093 us; speedup vs baseline: 1.0788x; 1.0016x over previous
//
#include <hip/hip_runtime.h>
#include <hip/hip_bf16.h>

#define B_ 32
#define N_ 512
#define H_ 128

typedef float f32x4 __attribute__((ext_vector_type(4)));
typedef short short8 __attribute__((ext_vector_type(8)));
typedef short short4v __attribute__((ext_vector_type(4)));

static __device__ __forceinline__ float bf2f(unsigned short u) {
  union { unsigned int ui; float f; } x;
  x.ui = ((unsigned int)u) << 16;
  return x.f;
}
static __device__ __forceinline__ unsigned short f2bf(float f) {
  __hip_bfloat16 h = __float2bfloat16(f);
  return *reinterpret_cast<unsigned short*>(&h);
}

// -------------------------------------------------------------------------
// Kernel 1: h[b,n,d] = silu(LN(s[b,n,:] @ W1[d,:] + b1[d]))
// stored TRANSPOSED bf16 into ws:  h_t[b][d][n]
// (unchanged — not the bottleneck per rocprof)
// -------------------------------------------------------------------------
__global__ __launch_bounds__(256) void lin_ln_silu_kernel(
    const float* __restrict__ s, const float* __restrict__ W1,
    const float* __restrict__ b1, unsigned short* __restrict__ h_t) {
  __shared__ float s_sh[32 * 132];            // [n][k] fp32, pad 132
  __shared__ unsigned short w_sh[128 * 132];  // [d][k] bf16, pad 132
  __shared__ unsigned short ht_sh[128 * 40];  // [d][n] bf16, pad 40
  const int t = threadIdx.x;
  const int b = blockIdx.y;
  const int n0 = blockIdx.x * 32;

#pragma unroll
  for (int r = 0; r < 16; ++r) {
    int q = t + 256 * r;
    int d = q >> 5, part = q & 31;
    float4 v = *reinterpret_cast<const float4*>(W1 + d * H_ + part * 4);
    short4v w;
    w.x = (short)f2bf(v.x); w.y = (short)f2bf(v.y);
    w.z = (short)f2bf(v.z); w.w = (short)f2bf(v.w);
    *reinterpret_cast<short4v*>(&w_sh[d * 132 + part * 4]) = w;
  }
#pragma unroll
  for (int r = 0; r < 4; ++r) {
    int q = t + 256 * r;
    int n = q >> 5, part = q & 31;
    float4 v = *reinterpret_cast<const float4*>(
        s + ((size_t)b * N_ + n0 + n) * H_ + part * 4);
    *reinterpret_cast<float4*>(&s_sh[n * 132 + part * 4]) = v;
  }
  __syncthreads();

  const int a = t & 15;
  const int g = t >> 4;
  float acc[2][8];
#pragma unroll
  for (int nn = 0; nn < 2; ++nn)
#pragma unroll
    for (int dd = 0; dd < 8; ++dd) acc[nn][dd] = 0.f;

  float bias[8];
#pragma unroll
  for (int dd = 0; dd < 8; ++dd) bias[dd] = b1[dd * 16 + a];

  for (int k = 0; k < 128; k += 4) {
    float wf[8][4];
#pragma unroll
    for (int dd = 0; dd < 8; ++dd) {
      short4v wv =
          *reinterpret_cast<const short4v*>(&w_sh[(dd * 16 + a) * 132 + k]);
      wf[dd][0] = bf2f((unsigned short)wv.x);
      wf[dd][1] = bf2f((unsigned short)wv.y);
      wf[dd][2] = bf2f((unsigned short)wv.z);
      wf[dd][3] = bf2f((unsigned short)wv.w);
    }
#pragma unroll
    for (int nn = 0; nn < 2; ++nn) {
      float4 sv =
          *reinterpret_cast<const float4*>(&s_sh[(nn * 16 + g) * 132 + k]);
#pragma unroll
      for (int dd = 0; dd < 8; ++dd) {
        acc[nn][dd] += sv.x * wf[dd][0] + sv.y * wf[dd][1] +
                       sv.z * wf[dd][2] + sv.w * wf[dd][3];
      }
    }
  }

#pragma unroll
  for (int nn = 0; nn < 2; ++nn) {
    float s1 = 0.f, s2 = 0.f;
#pragma unroll
    for (int dd = 0; dd < 8; ++dd) {
      float x = acc[nn][dd] + bias[dd];
      acc[nn][dd] = x;
      s1 += x;
      s2 += x * x;
    }
#pragma unroll
    for (int off = 8; off >= 1; off >>= 1) {
      s1 += __shfl_xor(s1, off);
      s2 += __shfl_xor(s2, off);
    }
    float mean = s1 * (1.f / 128.f);
    float var = s2 * (1.f / 128.f) - mean * mean;
    float rs = rsqrtf(var + 1e-5f);
#pragma unroll
    for (int dd = 0; dd < 8; ++dd) {
      float x = (acc[nn][dd] - mean) * rs;
      float y = x / (1.f + __expf(-x));  // silu
      ht_sh[(dd * 16 + a) * 40 + nn * 16 + g] = f2bf(y);
    }
  }
  __syncthreads();

#pragma unroll
  for (int r = 0; r < 2; ++r) {
    int q = t + 256 * r;
    int d = q >> 2, part = q & 3;
    float4 v = *reinterpret_cast<const float4*>(&ht_sh[d * 40 + part * 8]);
    *reinterpret_cast<float4*>(
        h_t + ((size_t)b * 128 + d) * 512 + n0 + part * 8) = v;
  }
}

// -------------------------------------------------------------------------
// Kernel 2: v[b,i,c,d] = sum_j mask[b,i,j]*ev[b,i,j,c]*h[b,j,d]  via MFMA.
// Per block: b, 16 i's. M-tile = 48 (m = c*16+il), N = 128 (d), K = 512 (j).
// This round: prefetch DISTANCE 2 (A/B register double-buffer, loop
// unrolled x2 for static indexing). Round r's STAGE consumes loads issued
// at round r-2 — two full rounds (~4 barriers + 2 MFMA phases + other
// blocks' work) cover the ~900cy HBM latency that distance-1 exposed
// (round 2: dur 63µs, 21% HBM, all pipes idle -> latency-bound).
// lgkm-only barriers keep both load sets in flight across barriers.
// Grid: (N/16, B), block 256 (4 waves; wave w covers d in [w*32, w*32+32)).
// -------------------------------------------------------------------------
__global__ __launch_bounds__(256, 4) void cfconv_mfma_kernel(
    const float* __restrict__ ev, const float* __restrict__ mask,
    const unsigned short* __restrict__ h_t, float* __restrict__ out) {
  __shared__ unsigned short ph[48 * 72];   // [m=c*16+il][j] bf16, pad 72
  __shared__ unsigned short hh[128 * 72];  // [d][j] bf16, pad 72
  const int t = threadIdx.x;
  const int b = blockIdx.y;
  const int i0 = blockIdx.x * 16;
  const int lane = t & 63;
  const int w = t >> 6;
  const int l15 = lane & 15;
  const int quad = lane >> 4;

  // staging roles
  const int si = t >> 4;  // 0..15  (i row)
  const int sj = t & 15;  // 0..15  (j group of 4)
  const int hd = t >> 3;  // base d for hh staging (q>>3 with r2 offset)
  const int hp = t & 7;   // j-part for hh staging
  const float* evbase =
      ev + ((size_t)(b * N_ + i0 + si)) * N_ * 3 + (size_t)sj * 12;
  const float* mbase = mask + ((size_t)(b * N_ + i0 + si)) * N_ + sj * 4;
  const unsigned short* hbase = h_t + (size_t)b * 128 * 512;

  f32x4 acc[3][2];
#pragma unroll
  for (int mt = 0; mt < 3; ++mt)
#pragma unroll
    for (int nt = 0; nt < 2; ++nt)
#pragma unroll
      for (int e = 0; e < 4; ++e) acc[mt][nt][e] = 0.f;

  // two prefetch register sets (distance-2 pipeline)
  float4 hvA[4], evvA[3], mkvA;
  float4 hvB[4], evvB[3], mkvB;

#define ISSUE(HV, EVV, MKV, JR)                                              \
  do {                                                                       \
    const int jn_ = (JR)*64;                                                 \
    _Pragma("unroll") for (int r2 = 0; r2 < 4; ++r2) {                       \
      int d_ = hd + 32 * r2;                                                 \
      HV[r2] = *reinterpret_cast<const float4*>(                             \
          hbase + (size_t)d_ * 512 + jn_ + hp * 8);                          \
    }                                                                        \
    _Pragma("unroll") for (int e_ = 0; e_ < 3; ++e_) {                       \
      EVV[e_] = *reinterpret_cast<const float4*>(evbase + (size_t)jn_ * 3 +  \
                                                 e_ * 4);                    \
    }                                                                        \
    MKV = *reinterpret_cast<const float4*>(mbase + jn_);                     \
  } while (0)

#define STAGE(HV, EVV, MKV)                                                  \
  do {                                                                       \
    _Pragma("unroll") for (int r2 = 0; r2 < 4; ++r2) {                       \
      int d_ = hd + 32 * r2;                                                 \
      *reinterpret_cast<float4*>(&hh[d_ * 72 + hp * 8]) = HV[r2];            \
    }                                                                        \
    float f_[12] = {EVV[0].x, EVV[0].y, EVV[0].z, EVV[0].w,                  \
                    EVV[1].x, EVV[1].y, EVV[1].z, EVV[1].w,                  \
                    EVV[2].x, EVV[2].y, EVV[2].z, EVV[2].w};                 \
    float mk_[4] = {MKV.x, MKV.y, MKV.z, MKV.w};                             \
    _Pragma("unroll") for (int c_ = 0; c_ < 3; ++c_) {                       \
      short4v pk_;                                                           \
      pk_.x = (short)f2bf(f_[0 * 3 + c_] * mk_[0]);                          \
      pk_.y = (short)f2bf(f_[1 * 3 + c_] * mk_[1]);                          \
      pk_.z = (short)f2bf(f_[2 * 3 + c_] * mk_[2]);                          \
      pk_.w = (short)f2bf(f_[3 * 3 + c_] * mk_[3]);                          \
      *reinterpret_cast<short4v*>(&ph[(c_ * 16 + si) * 72 + sj * 4]) = pk_;  \
    }                                                                        \
  } while (0)

#define COMPUTE()                                                            \
  do {                                                                       \
    _Pragma("unroll") for (int ks = 0; ks < 2; ++ks) {                       \
      short8 av[3], bv[2];                                                   \
      _Pragma("unroll") for (int mt = 0; mt < 3; ++mt) av[mt] =              \
          *reinterpret_cast<const short8*>(                                  \
              &ph[(mt * 16 + l15) * 72 + ks * 32 + quad * 8]);               \
      _Pragma("unroll") for (int nt = 0; nt < 2; ++nt) {                     \
        int d_ = w * 32 + nt * 16 + l15;                                     \
        bv[nt] = *reinterpret_cast<const short8*>(                           \
            &hh[d_ * 72 + ks * 32 + quad * 8]);                              \
      }                                                                      \
      _Pragma("unroll") for (int mt = 0; mt < 3; ++mt)                       \
          _Pragma("unroll") for (int nt = 0; nt < 2; ++nt) acc[mt][nt] =     \
          __builtin_amdgcn_mfma_f32_16x16x32_bf16(av[mt], bv[nt],            \
                                                  acc[mt][nt], 0, 0, 0);     \
    }                                                                        \
  } while (0)

#define SYNC_LGKM()                                   \
  do {                                                \
    asm volatile("s_waitcnt lgkmcnt(0)" ::: "memory"); \
    __builtin_amdgcn_s_barrier();                     \
  } while (0)

  // ---- prologue: rounds 0 and 1 in flight
  ISSUE(hvA, evvA, mkvA, 0);
  ISSUE(hvB, evvB, mkvB, 1);

#pragma unroll
  for (int rr = 0; rr < 4; ++rr) {
    // ---- round 2*rr (consumes set A)
    SYNC_LGKM();             // prev round's LDS readers done
    STAGE(hvA, evvA, mkvA);  // vmcnt waits land here (issued 2 rounds ago)
    SYNC_LGKM();             // ds_writes visible to all waves
    if (rr < 3) ISSUE(hvA, evvA, mkvA, 2 * rr + 2);
    COMPUTE();

    // ---- round 2*rr+1 (consumes set B)
    SYNC_LGKM();
    STAGE(hvB, evvB, mkvB);
    SYNC_LGKM();
    if (rr < 3) ISSUE(hvB, evvB, mkvB, 2 * rr + 3);
    COMPUTE();
  }

#undef ISSUE
#undef STAGE
#undef COMPUTE
#undef SYNC_LGKM

  // epilogue: C/D layout col=lane&15 (d), row=quad*4+reg (il); c = mt
#pragma unroll
  for (int mt = 0; mt < 3; ++mt) {
#pragma unroll
    for (int nt = 0; nt < 2; ++nt) {
      int d = w * 32 + nt * 16 + l15;
#pragma unroll
      for (int r = 0; r < 4; ++r) {
        int i = i0 + quad * 4 + r;
        out[(((size_t)b * N_ + i) * 3 + mt) * H_ + d] = acc[mt][nt][r];
      }
    }
  }
}

extern "C" void kernel_launch(void* const* d_in, const int* in_sizes, int n_in,
                              void* d_out, int out_size, void* d_ws,
                              size_t ws_size, hipStream_t stream) {
  const float* s = (const float*)d_in[0];
  const float* ev = (const float*)d_in[1];
  const float* mask = (const float*)d_in[2];
  const float* W1 = (const float*)d_in[3];
  const float* b1 = (const float*)d_in[4];
  float* out = (float*)d_out;
  // ws: h_t bf16 [B][128 d][512 n] = 4 MB
  unsigned short* h_t = (unsigned short*)d_ws;

  lin_ln_silu_kernel<<<dim3(N_ / 32, B_), 256, 0, stream>>>(s, W1, b1, h_t);
  cfconv_mfma_kernel<<<dim3(N_ / 16, B_), 256, 0, stream>>>(ev, mask, h_t, out);
}

// Round 4
// 211.603 us; speedup vs baseline: 1.0813x; 1.0023x over previous
//
#include <hip/hip_runtime.h>
#include <hip/hip_bf16.h>

#define B_ 32
#define N_ 512
#define H_ 128

typedef float f32x4 __attribute__((ext_vector_type(4)));
typedef short short8 __attribute__((ext_vector_type(8)));
typedef short short4v __attribute__((ext_vector_type(4)));

static __device__ __forceinline__ float bf2f(unsigned short u) {
  union { unsigned int ui; float f; } x;
  x.ui = ((unsigned int)u) << 16;
  return x.f;
}
static __device__ __forceinline__ unsigned short f2bf(float f) {
  __hip_bfloat16 h = __float2bfloat16(f);
  return *reinterpret_cast<unsigned short*>(&h);
}

// -------------------------------------------------------------------------
// Kernel 1: h[b,n,d] = silu(LN(s[b,n,:] @ W1[d,:] + b1[d]))
// stored TRANSPOSED bf16 into ws:  h_t[b][d][n]
// (unchanged — not the bottleneck per rocprof)
// -------------------------------------------------------------------------
__global__ __launch_bounds__(256) void lin_ln_silu_kernel(
    const float* __restrict__ s, const float* __restrict__ W1,
    const float* __restrict__ b1, unsigned short* __restrict__ h_t) {
  __shared__ float s_sh[32 * 132];            // [n][k] fp32, pad 132
  __shared__ unsigned short w_sh[128 * 132];  // [d][k] bf16, pad 132
  __shared__ unsigned short ht_sh[128 * 40];  // [d][n] bf16, pad 40
  const int t = threadIdx.x;
  const int b = blockIdx.y;
  const int n0 = blockIdx.x * 32;

#pragma unroll
  for (int r = 0; r < 16; ++r) {
    int q = t + 256 * r;
    int d = q >> 5, part = q & 31;
    float4 v = *reinterpret_cast<const float4*>(W1 + d * H_ + part * 4);
    short4v w;
    w.x = (short)f2bf(v.x); w.y = (short)f2bf(v.y);
    w.z = (short)f2bf(v.z); w.w = (short)f2bf(v.w);
    *reinterpret_cast<short4v*>(&w_sh[d * 132 + part * 4]) = w;
  }
#pragma unroll
  for (int r = 0; r < 4; ++r) {
    int q = t + 256 * r;
    int n = q >> 5, part = q & 31;
    float4 v = *reinterpret_cast<const float4*>(
        s + ((size_t)b * N_ + n0 + n) * H_ + part * 4);
    *reinterpret_cast<float4*>(&s_sh[n * 132 + part * 4]) = v;
  }
  __syncthreads();

  const int a = t & 15;
  const int g = t >> 4;
  float acc[2][8];
#pragma unroll
  for (int nn = 0; nn < 2; ++nn)
#pragma unroll
    for (int dd = 0; dd < 8; ++dd) acc[nn][dd] = 0.f;

  float bias[8];
#pragma unroll
  for (int dd = 0; dd < 8; ++dd) bias[dd] = b1[dd * 16 + a];

  for (int k = 0; k < 128; k += 4) {
    float wf[8][4];
#pragma unroll
    for (int dd = 0; dd < 8; ++dd) {
      short4v wv =
          *reinterpret_cast<const short4v*>(&w_sh[(dd * 16 + a) * 132 + k]);
      wf[dd][0] = bf2f((unsigned short)wv.x);
      wf[dd][1] = bf2f((unsigned short)wv.y);
      wf[dd][2] = bf2f((unsigned short)wv.z);
      wf[dd][3] = bf2f((unsigned short)wv.w);
    }
#pragma unroll
    for (int nn = 0; nn < 2; ++nn) {
      float4 sv =
          *reinterpret_cast<const float4*>(&s_sh[(nn * 16 + g) * 132 + k]);
#pragma unroll
      for (int dd = 0; dd < 8; ++dd) {
        acc[nn][dd] += sv.x * wf[dd][0] + sv.y * wf[dd][1] +
                       sv.z * wf[dd][2] + sv.w * wf[dd][3];
      }
    }
  }

#pragma unroll
  for (int nn = 0; nn < 2; ++nn) {
    float s1 = 0.f, s2 = 0.f;
#pragma unroll
    for (int dd = 0; dd < 8; ++dd) {
      float x = acc[nn][dd] + bias[dd];
      acc[nn][dd] = x;
      s1 += x;
      s2 += x * x;
    }
#pragma unroll
    for (int off = 8; off >= 1; off >>= 1) {
      s1 += __shfl_xor(s1, off);
      s2 += __shfl_xor(s2, off);
    }
    float mean = s1 * (1.f / 128.f);
    float var = s2 * (1.f / 128.f) - mean * mean;
    float rs = rsqrtf(var + 1e-5f);
#pragma unroll
    for (int dd = 0; dd < 8; ++dd) {
      float x = (acc[nn][dd] - mean) * rs;
      float y = x / (1.f + __expf(-x));  // silu
      ht_sh[(dd * 16 + a) * 40 + nn * 16 + g] = f2bf(y);
    }
  }
  __syncthreads();

#pragma unroll
  for (int r = 0; r < 2; ++r) {
    int q = t + 256 * r;
    int d = q >> 2, part = q & 3;
    float4 v = *reinterpret_cast<const float4*>(&ht_sh[d * 40 + part * 8]);
    *reinterpret_cast<float4*>(
        h_t + ((size_t)b * 128 + d) * 512 + n0 + part * 8) = v;
  }
}

// -------------------------------------------------------------------------
// Kernel 2: v[b,i,c,d] = sum_j mask[b,i,j]*ev[b,i,j,c]*h[b,j,d]  via MFMA.
// Per block: b, 16 i's. M-tile = 48 (m = c*16+il), N = 128 (d), K = 512 (j).
// Round 4 fix: the previous sync used `asm volatile(... ::: "memory")` —
// the memory clobber makes SIInsertWaitcnts drain vmcnt(0) at EVERY
// barrier, killing the prefetch pipeline (R1-R3 all ~63µs regardless of
// depth). Now: bare `s_waitcnt lgkmcnt(0)` + raw s_barrier (the m201
// pattern — raw s_barrier does NOT auto-drain vmcnt), with
// sched_barrier(0) on both sides as the compile-time ordering fence
// (stops LDS reads hoisting above / writes sinking below the sync).
// Distance-2 A/B register prefetch unchanged from round 3.
// Grid: (N/16, B), block 256 (4 waves; wave w covers d in [w*32, w*32+32)).
// -------------------------------------------------------------------------
__global__ __launch_bounds__(256, 4) void cfconv_mfma_kernel(
    const float* __restrict__ ev, const float* __restrict__ mask,
    const unsigned short* __restrict__ h_t, float* __restrict__ out) {
  __shared__ unsigned short ph[48 * 72];   // [m=c*16+il][j] bf16, pad 72
  __shared__ unsigned short hh[128 * 72];  // [d][j] bf16, pad 72
  const int t = threadIdx.x;
  const int b = blockIdx.y;
  const int i0 = blockIdx.x * 16;
  const int lane = t & 63;
  const int w = t >> 6;
  const int l15 = lane & 15;
  const int quad = lane >> 4;

  // staging roles
  const int si = t >> 4;  // 0..15  (i row)
  const int sj = t & 15;  // 0..15  (j group of 4)
  const int hd = t >> 3;  // base d for hh staging
  const int hp = t & 7;   // j-part for hh staging
  const float* evbase =
      ev + ((size_t)(b * N_ + i0 + si)) * N_ * 3 + (size_t)sj * 12;
  const float* mbase = mask + ((size_t)(b * N_ + i0 + si)) * N_ + sj * 4;
  const unsigned short* hbase = h_t + (size_t)b * 128 * 512;

  f32x4 acc[3][2];
#pragma unroll
  for (int mt = 0; mt < 3; ++mt)
#pragma unroll
    for (int nt = 0; nt < 2; ++nt)
#pragma unroll
      for (int e = 0; e < 4; ++e) acc[mt][nt][e] = 0.f;

  // two prefetch register sets (distance-2 pipeline)
  float4 hvA[4], evvA[3], mkvA;
  float4 hvB[4], evvB[3], mkvB;

#define ISSUE(HV, EVV, MKV, JR)                                              \
  do {                                                                       \
    const int jn_ = (JR)*64;                                                 \
    _Pragma("unroll") for (int r2 = 0; r2 < 4; ++r2) {                       \
      int d_ = hd + 32 * r2;                                                 \
      HV[r2] = *reinterpret_cast<const float4*>(                             \
          hbase + (size_t)d_ * 512 + jn_ + hp * 8);                          \
    }                                                                        \
    _Pragma("unroll") for (int e_ = 0; e_ < 3; ++e_) {                       \
      EVV[e_] = *reinterpret_cast<const float4*>(evbase + (size_t)jn_ * 3 +  \
                                                 e_ * 4);                    \
    }                                                                        \
    MKV = *reinterpret_cast<const float4*>(mbase + jn_);                     \
  } while (0)

#define STAGE(HV, EVV, MKV)                                                  \
  do {                                                                       \
    _Pragma("unroll") for (int r2 = 0; r2 < 4; ++r2) {                       \
      int d_ = hd + 32 * r2;                                                 \
      *reinterpret_cast<float4*>(&hh[d_ * 72 + hp * 8]) = HV[r2];            \
    }                                                                        \
    float f_[12] = {EVV[0].x, EVV[0].y, EVV[0].z, EVV[0].w,                  \
                    EVV[1].x, EVV[1].y, EVV[1].z, EVV[1].w,                  \
                    EVV[2].x, EVV[2].y, EVV[2].z, EVV[2].w};                 \
    float mk_[4] = {MKV.x, MKV.y, MKV.z, MKV.w};                             \
    _Pragma("unroll") for (int c_ = 0; c_ < 3; ++c_) {                       \
      short4v pk_;                                                           \
      pk_.x = (short)f2bf(f_[0 * 3 + c_] * mk_[0]);                          \
      pk_.y = (short)f2bf(f_[1 * 3 + c_] * mk_[1]);                          \
      pk_.z = (short)f2bf(f_[2 * 3 + c_] * mk_[2]);                          \
      pk_.w = (short)f2bf(f_[3 * 3 + c_] * mk_[3]);                          \
      *reinterpret_cast<short4v*>(&ph[(c_ * 16 + si) * 72 + sj * 4]) = pk_;  \
    }                                                                        \
  } while (0)

#define COMPUTE()                                                            \
  do {                                                                       \
    _Pragma("unroll") for (int ks = 0; ks < 2; ++ks) {                       \
      short8 av[3], bv[2];                                                   \
      _Pragma("unroll") for (int mt = 0; mt < 3; ++mt) av[mt] =              \
          *reinterpret_cast<const short8*>(                                  \
              &ph[(mt * 16 + l15) * 72 + ks * 32 + quad * 8]);               \
      _Pragma("unroll") for (int nt = 0; nt < 2; ++nt) {                     \
        int d_ = w * 32 + nt * 16 + l15;                                     \
        bv[nt] = *reinterpret_cast<const short8*>(                           \
            &hh[d_ * 72 + ks * 32 + quad * 8]);                              \
      }                                                                      \
      _Pragma("unroll") for (int mt = 0; mt < 3; ++mt)                       \
          _Pragma("unroll") for (int nt = 0; nt < 2; ++nt) acc[mt][nt] =     \
          __builtin_amdgcn_mfma_f32_16x16x32_bf16(av[mt], bv[nt],            \
                                                  acc[mt][nt], 0, 0, 0);     \
    }                                                                        \
  } while (0)

// lgkm-only sync: NO memory clobber on the asm (a "memory" clobber makes
// the backend drain vmcnt(0) here — the R1-R3 bug). sched_barrier(0)
// pins LDS-op ordering across the sync at compile time instead.
#define SYNC_LGKM()                          \
  do {                                       \
    __builtin_amdgcn_sched_barrier(0);       \
    asm volatile("s_waitcnt lgkmcnt(0)");    \
    __builtin_amdgcn_s_barrier();            \
    __builtin_amdgcn_sched_barrier(0);       \
  } while (0)

  // ---- prologue: rounds 0 and 1 in flight
  ISSUE(hvA, evvA, mkvA, 0);
  ISSUE(hvB, evvB, mkvB, 1);

#pragma unroll
  for (int rr = 0; rr < 4; ++rr) {
    // ---- round 2*rr (consumes set A)
    SYNC_LGKM();             // prev round's LDS readers done
    STAGE(hvA, evvA, mkvA);  // counted vmcnt wait lands here (set B stays
                             // in flight)
    SYNC_LGKM();             // my ds_writes committed -> barrier
    if (rr < 3) ISSUE(hvA, evvA, mkvA, 2 * rr + 2);
    COMPUTE();

    // ---- round 2*rr+1 (consumes set B)
    SYNC_LGKM();
    STAGE(hvB, evvB, mkvB);
    SYNC_LGKM();
    if (rr < 3) ISSUE(hvB, evvB, mkvB, 2 * rr + 3);
    COMPUTE();
  }

#undef ISSUE
#undef STAGE
#undef COMPUTE
#undef SYNC_LGKM

  // epilogue: C/D layout col=lane&15 (d), row=quad*4+reg (il); c = mt
#pragma unroll
  for (int mt = 0; mt < 3; ++mt) {
#pragma unroll
    for (int nt = 0; nt < 2; ++nt) {
      int d = w * 32 + nt * 16 + l15;
#pragma unroll
      for (int r = 0; r < 4; ++r) {
        int i = i0 + quad * 4 + r;
        out[(((size_t)b * N_ + i) * 3 + mt) * H_ + d] = acc[mt][nt][r];
      }
    }
  }
}

extern "C" void kernel_launch(void* const* d_in, const int* in_sizes, int n_in,
                              void* d_out, int out_size, void* d_ws,
                              size_t ws_size, hipStream_t stream) {
  const float* s = (const float*)d_in[0];
  const float* ev = (const float*)d_in[1];
  const float* mask = (const float*)d_in[2];
  const float* W1 = (const float*)d_in[3];
  const float* b1 = (const float*)d_in[4];
  float* out = (float*)d_out;
  // ws: h_t bf16 [B][128 d][512 n] = 4 MB
  unsigned short* h_t = (unsigned short*)d_ws;

  lin_ln_silu_kernel<<<dim3(N_ / 32, B_), 256, 0, stream>>>(s, W1, b1, h_t);
  cfconv_mfma_kernel<<<dim3(N_ / 16, B_), 256, 0, stream>>>(ev, mask, h_t, out);
}

// Round 5
// 206.840 us; speedup vs baseline: 1.1062x; 1.0230x over previous
//
#include <hip/hip_runtime.h>
#include <hip/hip_bf16.h>

#define B_ 32
#define N_ 512
#define H_ 128

typedef float f32x4 __attribute__((ext_vector_type(4)));
typedef short short8 __attribute__((ext_vector_type(8)));
typedef short short4v __attribute__((ext_vector_type(4)));

static __device__ __forceinline__ float bf2f(unsigned short u) {
  union { unsigned int ui; float f; } x;
  x.ui = ((unsigned int)u) << 16;
  return x.f;
}
static __device__ __forceinline__ unsigned short f2bf(float f) {
  __hip_bfloat16 h = __float2bfloat16(f);
  return *reinterpret_cast<unsigned short*>(&h);
}

// -------------------------------------------------------------------------
// Kernel 1: h[b,n,d] = silu(LN(s[b,n,:] @ W1[d,:] + b1[d]))
// stored TRANSPOSED bf16 into ws:  h_t[b][d][n]
// (unchanged — not the bottleneck per rocprof)
// -------------------------------------------------------------------------
__global__ __launch_bounds__(256) void lin_ln_silu_kernel(
    const float* __restrict__ s, const float* __restrict__ W1,
    const float* __restrict__ b1, unsigned short* __restrict__ h_t) {
  __shared__ float s_sh[32 * 132];            // [n][k] fp32, pad 132
  __shared__ unsigned short w_sh[128 * 132];  // [d][k] bf16, pad 132
  __shared__ unsigned short ht_sh[128 * 40];  // [d][n] bf16, pad 40
  const int t = threadIdx.x;
  const int b = blockIdx.y;
  const int n0 = blockIdx.x * 32;

#pragma unroll
  for (int r = 0; r < 16; ++r) {
    int q = t + 256 * r;
    int d = q >> 5, part = q & 31;
    float4 v = *reinterpret_cast<const float4*>(W1 + d * H_ + part * 4);
    short4v w;
    w.x = (short)f2bf(v.x); w.y = (short)f2bf(v.y);
    w.z = (short)f2bf(v.z); w.w = (short)f2bf(v.w);
    *reinterpret_cast<short4v*>(&w_sh[d * 132 + part * 4]) = w;
  }
#pragma unroll
  for (int r = 0; r < 4; ++r) {
    int q = t + 256 * r;
    int n = q >> 5, part = q & 31;
    float4 v = *reinterpret_cast<const float4*>(
        s + ((size_t)b * N_ + n0 + n) * H_ + part * 4);
    *reinterpret_cast<float4*>(&s_sh[n * 132 + part * 4]) = v;
  }
  __syncthreads();

  const int a = t & 15;
  const int g = t >> 4;
  float acc[2][8];
#pragma unroll
  for (int nn = 0; nn < 2; ++nn)
#pragma unroll
    for (int dd = 0; dd < 8; ++dd) acc[nn][dd] = 0.f;

  float bias[8];
#pragma unroll
  for (int dd = 0; dd < 8; ++dd) bias[dd] = b1[dd * 16 + a];

  for (int k = 0; k < 128; k += 4) {
    float wf[8][4];
#pragma unroll
    for (int dd = 0; dd < 8; ++dd) {
      short4v wv =
          *reinterpret_cast<const short4v*>(&w_sh[(dd * 16 + a) * 132 + k]);
      wf[dd][0] = bf2f((unsigned short)wv.x);
      wf[dd][1] = bf2f((unsigned short)wv.y);
      wf[dd][2] = bf2f((unsigned short)wv.z);
      wf[dd][3] = bf2f((unsigned short)wv.w);
    }
#pragma unroll
    for (int nn = 0; nn < 2; ++nn) {
      float4 sv =
          *reinterpret_cast<const float4*>(&s_sh[(nn * 16 + g) * 132 + k]);
#pragma unroll
      for (int dd = 0; dd < 8; ++dd) {
        acc[nn][dd] += sv.x * wf[dd][0] + sv.y * wf[dd][1] +
                       sv.z * wf[dd][2] + sv.w * wf[dd][3];
      }
    }
  }

#pragma unroll
  for (int nn = 0; nn < 2; ++nn) {
    float s1 = 0.f, s2 = 0.f;
#pragma unroll
    for (int dd = 0; dd < 8; ++dd) {
      float x = acc[nn][dd] + bias[dd];
      acc[nn][dd] = x;
      s1 += x;
      s2 += x * x;
    }
#pragma unroll
    for (int off = 8; off >= 1; off >>= 1) {
      s1 += __shfl_xor(s1, off);
      s2 += __shfl_xor(s2, off);
    }
    float mean = s1 * (1.f / 128.f);
    float var = s2 * (1.f / 128.f) - mean * mean;
    float rs = rsqrtf(var + 1e-5f);
#pragma unroll
    for (int dd = 0; dd < 8; ++dd) {
      float x = (acc[nn][dd] - mean) * rs;
      float y = x / (1.f + __expf(-x));  // silu
      ht_sh[(dd * 16 + a) * 40 + nn * 16 + g] = f2bf(y);
    }
  }
  __syncthreads();

#pragma unroll
  for (int r = 0; r < 2; ++r) {
    int q = t + 256 * r;
    int d = q >> 2, part = q & 3;
    float4 v = *reinterpret_cast<const float4*>(&ht_sh[d * 40 + part * 8]);
    *reinterpret_cast<float4*>(
        h_t + ((size_t)b * 128 + d) * 512 + n0 + part * 8) = v;
  }
}

// -------------------------------------------------------------------------
// Kernel 2: v[b,i,c,d] = sum_j mask[b,i,j]*ev[b,i,j,c]*h[b,j,d]  via MFMA.
// Per block: b, 16 i's. M-tile = 48 (m=c*16+il), N = 128 (d), K = 512 (j).
//
// Round 5: ASM-PINNED prefetch. R2-R4 were all ~62µs because the backend
// scheduler SANK the plain-C prefetch loads to their STAGE uses (proof:
// VGPR_Count 40-52 — the 64 prefetch regs never existed; R1, where they
// did exist, spilled). Volatile inline-asm global_load_dwordx4 cannot be
// reordered vs the volatile barrier/waitcnt asm, and "=v" outputs pin the
// registers. Waits are counted (vmcnt(4)), never a drain.
// Depth: ev/mask (HBM, ~900cy) distance-2 (A/B sets); h_t (L2-resident,
// ~250cy) distance-1 single set. 12 vmem ops in flight per wave spanning
// the compute phase -> MLP up, convoy broken.
// Per-round issue order (steady state r): [hv(r+1), evmk(r+2)] after
// sync2; wait at round r = vmcnt(4) (retires hv(r)+evmk(r), leaves the
// newest 4); round 7 waits vmcnt(0).
// Grid: (N/16, B), block 256 (4 waves; wave w covers d in [w*32,w*32+32)).
// -------------------------------------------------------------------------
__global__ __launch_bounds__(256, 4) void cfconv_mfma_kernel(
    const float* __restrict__ ev, const float* __restrict__ mask,
    const unsigned short* __restrict__ h_t, float* __restrict__ out) {
  __shared__ unsigned short ph[48 * 72];   // [m=c*16+il][j] bf16, pad 72
  __shared__ unsigned short hh[128 * 72];  // [d][j] bf16, pad 72
  const int t = threadIdx.x;
  const int b = blockIdx.y;
  const int i0 = blockIdx.x * 16;
  const int lane = t & 63;
  const int w = t >> 6;
  const int l15 = lane & 15;
  const int quad = lane >> 4;

  // staging roles
  const int si = t >> 4;  // 0..15  (i row)
  const int sj = t & 15;  // 0..15  (j group of 4)
  const int hd = t >> 3;  // base d for hh staging
  const int hp = t & 7;   // j-part for hh staging
  const float* evbase =
      ev + ((size_t)(b * N_ + i0 + si)) * N_ * 3 + (size_t)sj * 12;
  const float* mbase = mask + ((size_t)(b * N_ + i0 + si)) * N_ + sj * 4;
  const unsigned short* hbase = h_t + (size_t)b * 128 * 512;

  f32x4 acc[3][2];
#pragma unroll
  for (int mt = 0; mt < 3; ++mt)
#pragma unroll
    for (int nt = 0; nt < 2; ++nt)
#pragma unroll
      for (int e = 0; e < 4; ++e) acc[mt][nt][e] = 0.f;

  // prefetch registers: hv distance-1 (single set), ev/mask distance-2
  f32x4 hv[4];
  f32x4 evvA[3], evvB[3];
  f32x4 mkvA, mkvB;

#define STR2_(x) #x
#define VMWAIT(n) asm volatile("s_waitcnt vmcnt(" STR2_(n) ")")

// volatile asm load: cannot be reordered vs other volatile asm (the
// barrier/waitcnt asm), so issue placement is pinned.
#define ALOAD4(DST, PTR) \
  asm volatile("global_load_dwordx4 %0, %1, off" : "=v"(DST) : "v"(PTR))

#define ISSUE_HV(JR)                                                      \
  do {                                                                    \
    _Pragma("unroll") for (int r2_ = 0; r2_ < 4; ++r2_) {                 \
      const unsigned short* p_ =                                          \
          hbase + (size_t)(hd + 32 * r2_) * 512 + (JR)*64 + hp * 8;       \
      ALOAD4(hv[r2_], p_);                                                \
    }                                                                     \
  } while (0)

#define ISSUE_EV(EVV, MKV, JR)                                            \
  do {                                                                    \
    _Pragma("unroll") for (int e_ = 0; e_ < 3; ++e_) {                    \
      const float* p_ = evbase + (size_t)(JR)*192 + e_ * 4;               \
      ALOAD4(EVV[e_], p_);                                                \
    }                                                                     \
    const float* pm_ = mbase + (JR)*64;                                   \
    ALOAD4(MKV, pm_);                                                     \
  } while (0)

#define STAGE(EVV, MKV)                                                   \
  do {                                                                    \
    _Pragma("unroll") for (int r2_ = 0; r2_ < 4; ++r2_) {                 \
      *reinterpret_cast<f32x4*>(&hh[(hd + 32 * r2_) * 72 + hp * 8]) =     \
          hv[r2_];                                                        \
    }                                                                     \
    float f_[12] = {EVV[0][0], EVV[0][1], EVV[0][2], EVV[0][3],           \
                    EVV[1][0], EVV[1][1], EVV[1][2], EVV[1][3],           \
                    EVV[2][0], EVV[2][1], EVV[2][2], EVV[2][3]};          \
    float mk_[4] = {MKV[0], MKV[1], MKV[2], MKV[3]};                      \
    _Pragma("unroll") for (int c_ = 0; c_ < 3; ++c_) {                    \
      short4v pk_;                                                        \
      pk_.x = (short)f2bf(f_[0 * 3 + c_] * mk_[0]);                       \
      pk_.y = (short)f2bf(f_[1 * 3 + c_] * mk_[1]);                       \
      pk_.z = (short)f2bf(f_[2 * 3 + c_] * mk_[2]);                       \
      pk_.w = (short)f2bf(f_[3 * 3 + c_] * mk_[3]);                       \
      *reinterpret_cast<short4v*>(&ph[(c_ * 16 + si) * 72 + sj * 4]) =    \
          pk_;                                                            \
    }                                                                     \
  } while (0)

#define COMPUTE()                                                         \
  do {                                                                    \
    _Pragma("unroll") for (int ks = 0; ks < 2; ++ks) {                    \
      short8 av[3], bv[2];                                                \
      _Pragma("unroll") for (int mt = 0; mt < 3; ++mt) av[mt] =           \
          *reinterpret_cast<const short8*>(                               \
              &ph[(mt * 16 + l15) * 72 + ks * 32 + quad * 8]);            \
      _Pragma("unroll") for (int nt = 0; nt < 2; ++nt) {                  \
        int d_ = w * 32 + nt * 16 + l15;                                  \
        bv[nt] = *reinterpret_cast<const short8*>(                        \
            &hh[d_ * 72 + ks * 32 + quad * 8]);                          \
      }                                                                   \
      _Pragma("unroll") for (int mt = 0; mt < 3; ++mt)                    \
          _Pragma("unroll") for (int nt = 0; nt < 2; ++nt) acc[mt][nt] =  \
          __builtin_amdgcn_mfma_f32_16x16x32_bf16(av[mt], bv[nt],         \
                                                  acc[mt][nt], 0, 0, 0);  \
    }                                                                     \
  } while (0)

// lgkm-only sync: no memory clobber (would force vmcnt(0) drain);
// sched_barrier(0) pins LDS-op ordering across the sync at compile time.
#define SYNC_LGKM()                          \
  do {                                       \
    __builtin_amdgcn_sched_barrier(0);       \
    asm volatile("s_waitcnt lgkmcnt(0)");    \
    __builtin_amdgcn_s_barrier();            \
    __builtin_amdgcn_sched_barrier(0);       \
  } while (0)

// One pipeline round. VMN: counted vmem wait (literal). EVV/MKV: the
// ev/mask set this round consumes (and re-issues for JEV if JEV<8).
#define ROUND(VMN, EVV, MKV, JHV, JEV)       \
  do {                                       \
    SYNC_LGKM();                             \
    VMWAIT(VMN);                             \
    __builtin_amdgcn_sched_barrier(0);       \
    STAGE(EVV, MKV);                         \
    SYNC_LGKM();                             \
    if ((JHV) < 8) ISSUE_HV(JHV);            \
    if ((JEV) < 8) ISSUE_EV(EVV, MKV, JEV);  \
    __builtin_amdgcn_sched_barrier(0);       \
    COMPUTE();                               \
  } while (0)

  // ---- prologue: hv(0), evmk(0), evmk(1) in flight (12 ops)
  ISSUE_HV(0);
  ISSUE_EV(evvA, mkvA, 0);
  ISSUE_EV(evvB, mkvB, 1);

  ROUND(4, evvA, mkvA, 1, 2);  // r0
  ROUND(4, evvB, mkvB, 2, 3);  // r1
  ROUND(4, evvA, mkvA, 3, 4);  // r2
  ROUND(4, evvB, mkvB, 4, 5);  // r3
  ROUND(4, evvA, mkvA, 5, 6);  // r4
  ROUND(4, evvB, mkvB, 6, 7);  // r5
  ROUND(4, evvA, mkvA, 7, 8);  // r6 (issues hv(7) only)
  ROUND(0, evvB, mkvB, 8, 9);  // r7 (no issues, drain)

#undef ROUND
#undef SYNC_LGKM
#undef COMPUTE
#undef STAGE
#undef ISSUE_EV
#undef ISSUE_HV
#undef ALOAD4
#undef VMWAIT
#undef STR2_

  // epilogue: C/D layout col=lane&15 (d), row=quad*4+reg (il); c = mt
#pragma unroll
  for (int mt = 0; mt < 3; ++mt) {
#pragma unroll
    for (int nt = 0; nt < 2; ++nt) {
      int d = w * 32 + nt * 16 + l15;
#pragma unroll
      for (int r = 0; r < 4; ++r) {
        int i = i0 + quad * 4 + r;
        out[(((size_t)b * N_ + i) * 3 + mt) * H_ + d] = acc[mt][nt][r];
      }
    }
  }
}

extern "C" void kernel_launch(void* const* d_in, const int* in_sizes, int n_in,
                              void* d_out, int out_size, void* d_ws,
                              size_t ws_size, hipStream_t stream) {
  const float* s = (const float*)d_in[0];
  const float* ev = (const float*)d_in[1];
  const float* mask = (const float*)d_in[2];
  const float* W1 = (const float*)d_in[3];
  const float* b1 = (const float*)d_in[4];
  float* out = (float*)d_out;
  // ws: h_t bf16 [B][128 d][512 n] = 4 MB
  unsigned short* h_t = (unsigned short*)d_ws;

  lin_ln_silu_kernel<<<dim3(N_ / 32, B_), 256, 0, stream>>>(s, W1, b1, h_t);
  cfconv_mfma_kernel<<<dim3(N_ / 16, B_), 256, 0, stream>>>(ev, mask, h_t, out);
}

// Round 6
// 206.525 us; speedup vs baseline: 1.1078x; 1.0015x over previous
//
#include <hip/hip_runtime.h>
#include <hip/hip_bf16.h>

#define B_ 32
#define N_ 512
#define H_ 128

typedef float f32x4 __attribute__((ext_vector_type(4)));
typedef short short8 __attribute__((ext_vector_type(8)));
typedef short short4v __attribute__((ext_vector_type(4)));

static __device__ __forceinline__ float bf2f(unsigned short u) {
  union { unsigned int ui; float f; } x;
  x.ui = ((unsigned int)u) << 16;
  return x.f;
}
static __device__ __forceinline__ unsigned short f2bf(float f) {
  __hip_bfloat16 h = __float2bfloat16(f);
  return *reinterpret_cast<unsigned short*>(&h);
}

// async global->LDS DMA, 16B per lane. LDS dest must be the WAVE-UNIFORM
// base (HW adds lane*16); global src is per-lane.
static __device__ __forceinline__ void gld16(const void* g, void* l) {
  __builtin_amdgcn_global_load_lds(
      (const __attribute__((address_space(1))) unsigned int*)g,
      (__attribute__((address_space(3))) unsigned int*)l, 16, 0, 0);
}

// -------------------------------------------------------------------------
// Kernel 1: h[b,n,d] = silu(LN(s[b,n,:] @ W1[d,:] + b1[d]))
// stored TRANSPOSED bf16 into ws:  h_t[b][d][n]
// (unchanged — not the bottleneck per rocprof)
// -------------------------------------------------------------------------
__global__ __launch_bounds__(256) void lin_ln_silu_kernel(
    const float* __restrict__ s, const float* __restrict__ W1,
    const float* __restrict__ b1, unsigned short* __restrict__ h_t) {
  __shared__ float s_sh[32 * 132];            // [n][k] fp32, pad 132
  __shared__ unsigned short w_sh[128 * 132];  // [d][k] bf16, pad 132
  __shared__ unsigned short ht_sh[128 * 40];  // [d][n] bf16, pad 40
  const int t = threadIdx.x;
  const int b = blockIdx.y;
  const int n0 = blockIdx.x * 32;

#pragma unroll
  for (int r = 0; r < 16; ++r) {
    int q = t + 256 * r;
    int d = q >> 5, part = q & 31;
    float4 v = *reinterpret_cast<const float4*>(W1 + d * H_ + part * 4);
    short4v w;
    w.x = (short)f2bf(v.x); w.y = (short)f2bf(v.y);
    w.z = (short)f2bf(v.z); w.w = (short)f2bf(v.w);
    *reinterpret_cast<short4v*>(&w_sh[d * 132 + part * 4]) = w;
  }
#pragma unroll
  for (int r = 0; r < 4; ++r) {
    int q = t + 256 * r;
    int n = q >> 5, part = q & 31;
    float4 v = *reinterpret_cast<const float4*>(
        s + ((size_t)b * N_ + n0 + n) * H_ + part * 4);
    *reinterpret_cast<float4*>(&s_sh[n * 132 + part * 4]) = v;
  }
  __syncthreads();

  const int a = t & 15;
  const int g = t >> 4;
  float acc[2][8];
#pragma unroll
  for (int nn = 0; nn < 2; ++nn)
#pragma unroll
    for (int dd = 0; dd < 8; ++dd) acc[nn][dd] = 0.f;

  float bias[8];
#pragma unroll
  for (int dd = 0; dd < 8; ++dd) bias[dd] = b1[dd * 16 + a];

  for (int k = 0; k < 128; k += 4) {
    float wf[8][4];
#pragma unroll
    for (int dd = 0; dd < 8; ++dd) {
      short4v wv =
          *reinterpret_cast<const short4v*>(&w_sh[(dd * 16 + a) * 132 + k]);
      wf[dd][0] = bf2f((unsigned short)wv.x);
      wf[dd][1] = bf2f((unsigned short)wv.y);
      wf[dd][2] = bf2f((unsigned short)wv.z);
      wf[dd][3] = bf2f((unsigned short)wv.w);
    }
#pragma unroll
    for (int nn = 0; nn < 2; ++nn) {
      float4 sv =
          *reinterpret_cast<const float4*>(&s_sh[(nn * 16 + g) * 132 + k]);
#pragma unroll
      for (int dd = 0; dd < 8; ++dd) {
        acc[nn][dd] += sv.x * wf[dd][0] + sv.y * wf[dd][1] +
                       sv.z * wf[dd][2] + sv.w * wf[dd][3];
      }
    }
  }

#pragma unroll
  for (int nn = 0; nn < 2; ++nn) {
    float s1 = 0.f, s2 = 0.f;
#pragma unroll
    for (int dd = 0; dd < 8; ++dd) {
      float x = acc[nn][dd] + bias[dd];
      acc[nn][dd] = x;
      s1 += x;
      s2 += x * x;
    }
#pragma unroll
    for (int off = 8; off >= 1; off >>= 1) {
      s1 += __shfl_xor(s1, off);
      s2 += __shfl_xor(s2, off);
    }
    float mean = s1 * (1.f / 128.f);
    float var = s2 * (1.f / 128.f) - mean * mean;
    float rs = rsqrtf(var + 1e-5f);
#pragma unroll
    for (int dd = 0; dd < 8; ++dd) {
      float x = (acc[nn][dd] - mean) * rs;
      float y = x / (1.f + __expf(-x));  // silu
      ht_sh[(dd * 16 + a) * 40 + nn * 16 + g] = f2bf(y);
    }
  }
  __syncthreads();

#pragma unroll
  for (int r = 0; r < 2; ++r) {
    int q = t + 256 * r;
    int d = q >> 2, part = q & 3;
    float4 v = *reinterpret_cast<const float4*>(&ht_sh[d * 40 + part * 8]);
    *reinterpret_cast<float4*>(
        h_t + ((size_t)b * 128 + d) * 512 + n0 + part * 8) = v;
  }
}

// -------------------------------------------------------------------------
// Kernel 2: v[b,i,c,d] = sum_j mask[b,i,j]*ev[b,i,j,c]*h[b,j,d]  via MFMA.
// Per block: b, 16 i's. M-tile = 48 (m=c*16+il), N=128 (d), K=512 (j).
//
// Round 6: global_load_lds double-buffered tiles (m201 pattern).
// R0-R5 showed register-staged loads land at 61-67us regardless of
// pipelining: the cost is the staging machinery (ev's 48B-stride lane
// pattern touches 3x the cache lines per instr; 15 VMEM + 7 ds_write +
// ~40 VALU unpack per thread-round). Now:
//  - ev staged RAW fp32 [16][192] via gld16: per-lane CONTIGUOUS global
//    (minimal transactions), zero VGPR staging. ev*mask->bf16 conversion
//    happens post-barrier as an LDS->LDS phase (3x ds_read_b128 + regs).
//  - h_t staged via gld16 into UNPADDED [128][64] with source-side XOR
//    swizzle (linear LDS dest + inverse-swizzled per-lane global source;
//    COMPUTE reads with matching XOR -> bank-conflict-free, rule #21).
//  - mask in asm-pinned regs (thread-local under (si,sj) mapping).
//  - Double-buffered tiles, counted vmcnt(7) (never drained mid-loop),
//    raw s_barrier + lgkm-only waits, sched_barrier(0) fences.
// LDS = 24576(ev x2) + 32768(hh x2) + 6912(ph) = 64256 B -> 2 blocks/CU.
// In-flight: ~28KB/block DMA continuously -> BW no longer latency-capped.
// Grid: (N/16, B), block 256 (4 waves; wave w covers d in [w*32,w*32+32)).
// -------------------------------------------------------------------------
__global__ __launch_bounds__(256, 2) void cfconv_mfma_kernel(
    const float* __restrict__ ev, const float* __restrict__ mask,
    const unsigned short* __restrict__ h_t, float* __restrict__ out) {
  __shared__ float evr[2][3072];           // [16][192] fp32 raw ev tile
  __shared__ unsigned short hhs[2][8192];  // [128][64] bf16, XOR-swizzled
  __shared__ unsigned short ph[48 * 72];   // [m=c*16+i][j] bf16, pad 72
  const int t = threadIdx.x;
  const int b = blockIdx.y;
  const int i0 = blockIdx.x * 16;
  const int w = t >> 6, l = t & 63;
  const int l15 = l & 15, quad = l >> 4;
  const int si = t >> 4, sj = t & 15;  // conversion roles
  const int xr = (l15 & 7) << 3;       // hh read swizzle (ushort units)

  // ---- per-thread constant addressing (computed once) ----
  // ev tile: 16 rows x 768B (row stride in global = 6144B). 12 wave-ops of
  // 1024B each; op (w*3+e), lane l covers tile byte L*16, L=(w*3+e)*64+l.
  const char* evB = (const char*)ev + ((size_t)(b * N_) + i0) * (N_ * 12);
  int ev_row[3], ev_off[3];
#pragma unroll
  for (int e = 0; e < 3; ++e) {
    int L = (w * 3 + e) * 64 + l;
    ev_row[e] = L / 48;                  // tile i row
    ev_off[e] = (L - ev_row[e] * 48) * 16;  // byte offset within row slice
  }
  // hh tile: wave w, op r2 -> rows [r2*32+w*8, +8). lane l -> row
  // rows_start+(l>>3), within-row byte (l&7)*16, SOURCE col pre-swizzled
  // by XOR (row&7)<<4 so linear DMA + swizzled read = conflict-free.
  const char* hhB = (const char*)h_t + (size_t)b * (128 * 512 * 2);
  int hh_go[4];
#pragma unroll
  for (int r2 = 0; r2 < 4; ++r2)
    hh_go[r2] = ((r2 * 32 + w * 8 + (l >> 3)) << 10) +
                ((((l & 7) ^ (l >> 3))) << 4);
  const float* mB = mask + ((size_t)(b * N_) + i0 + si) * N_ + sj * 4;

  f32x4 acc[3][2];
#pragma unroll
  for (int mt = 0; mt < 3; ++mt)
#pragma unroll
    for (int nt = 0; nt < 2; ++nt)
#pragma unroll
      for (int e = 0; e < 4; ++e) acc[mt][nt][e] = 0.f;

  f32x4 mkA, mkB;  // mask prefetch regs (A/B by round parity)

#define SB() __builtin_amdgcn_sched_barrier(0)
#define ALOAD4(DST, PTR) \
  asm volatile("global_load_dwordx4 %0, %1, off" : "=v"(DST) : "v"(PTR))

// 7 DMA ops per tile: 3 ev + 4 hh. LDS dests are wave-uniform bases.
#define ISSUE_TILE(Q, JR)                                              \
  do {                                                                 \
    _Pragma("unroll") for (int e_ = 0; e_ < 3; ++e_)                   \
        gld16(evB + (size_t)ev_row[e_] * 6144 + (JR)*768 + ev_off[e_], \
              (char*)&evr[Q][0] + (w * 3 + e_) * 1024);                \
    _Pragma("unroll") for (int r2_ = 0; r2_ < 4; ++r2_)                \
        gld16(hhB + hh_go[r2_] + (JR)*128,                             \
              (char*)&hhs[Q][0] + (r2_ * 32 + w * 8) * 128);           \
  } while (0)

#define ISSUE_MASK(MK, JR)                 \
  do {                                     \
    const float* pm_ = mB + (JR)*64;       \
    ALOAD4(MK, pm_);                       \
  } while (0)

// LDS->LDS conversion: thread (si,sj) reads its raw ev 48B (3x b128,
// 2-way banks within quad = free) + its mask regs -> 3x b64 ph writes.
#define CONVERT(P, MK)                                                   \
  do {                                                                   \
    const float* ep_ = &evr[P][si * 192 + sj * 12];                      \
    f32x4 e0_ = *reinterpret_cast<const f32x4*>(ep_);                    \
    f32x4 e1_ = *reinterpret_cast<const f32x4*>(ep_ + 4);                \
    f32x4 e2_ = *reinterpret_cast<const f32x4*>(ep_ + 8);                \
    float f_[12] = {e0_[0], e0_[1], e0_[2], e0_[3], e1_[0], e1_[1],      \
                    e1_[2], e1_[3], e2_[0], e2_[1], e2_[2], e2_[3]};     \
    float mk_[4] = {MK[0], MK[1], MK[2], MK[3]};                         \
    _Pragma("unroll") for (int c_ = 0; c_ < 3; ++c_) {                   \
      short4v pk_;                                                       \
      pk_.x = (short)f2bf(f_[0 * 3 + c_] * mk_[0]);                      \
      pk_.y = (short)f2bf(f_[1 * 3 + c_] * mk_[1]);                      \
      pk_.z = (short)f2bf(f_[2 * 3 + c_] * mk_[2]);                      \
      pk_.w = (short)f2bf(f_[3 * 3 + c_] * mk_[3]);                      \
      *reinterpret_cast<short4v*>(&ph[(c_ * 16 + si) * 72 + sj * 4]) =   \
          pk_;                                                           \
    }                                                                    \
  } while (0)

#define COMPUTE(P)                                                        \
  do {                                                                    \
    _Pragma("unroll") for (int ks = 0; ks < 2; ++ks) {                    \
      short8 av[3], bv[2];                                                \
      _Pragma("unroll") for (int mt = 0; mt < 3; ++mt) av[mt] =           \
          *reinterpret_cast<const short8*>(                               \
              &ph[(mt * 16 + l15) * 72 + ks * 32 + quad * 8]);            \
      _Pragma("unroll") for (int nt = 0; nt < 2; ++nt) {                  \
        int d_ = w * 32 + nt * 16 + l15;                                  \
        bv[nt] = *reinterpret_cast<const short8*>(                        \
            &hhs[P][d_ * 64 + ((ks * 32 + quad * 8) ^ xr)]);              \
      }                                                                   \
      _Pragma("unroll") for (int mt = 0; mt < 3; ++mt)                    \
          _Pragma("unroll") for (int nt = 0; nt < 2; ++nt) acc[mt][nt] =  \
          __builtin_amdgcn_mfma_f32_16x16x32_bf16(av[mt], bv[nt],         \
                                                  acc[mt][nt], 0, 0, 0);  \
    }                                                                     \
  } while (0)

// Steady round r (r<7): join-barrier; issue tile r+1 (other buf);
// vmcnt(7) = retire tile r + mask r, keep tile r+1 flying; barrier;
// convert; issue next mask; lgkm barrier; MFMA.
#define ROUND7(P, Q, MKC, MKN, JN)            \
  do {                                        \
    SB(); __builtin_amdgcn_s_barrier(); SB(); \
    ISSUE_TILE(Q, JN);                        \
    SB();                                     \
    asm volatile("s_waitcnt vmcnt(7)");       \
    SB();                                     \
    __builtin_amdgcn_s_barrier(); SB();       \
    CONVERT(P, MKC);                          \
    ISSUE_MASK(MKN, JN);                      \
    SB();                                     \
    asm volatile("s_waitcnt lgkmcnt(0)");     \
    __builtin_amdgcn_s_barrier(); SB();       \
    COMPUTE(P);                               \
  } while (0)

#define ROUND_LAST(P, MKC)                    \
  do {                                        \
    SB(); __builtin_amdgcn_s_barrier(); SB(); \
    asm volatile("s_waitcnt vmcnt(0)");       \
    SB();                                     \
    __builtin_amdgcn_s_barrier(); SB();       \
    CONVERT(P, MKC);                          \
    SB();                                     \
    asm volatile("s_waitcnt lgkmcnt(0)");     \
    __builtin_amdgcn_s_barrier(); SB();       \
    COMPUTE(P);                               \
  } while (0)

  // ---- prologue: tile 0 + mask 0 in flight (8 VMEM ops) ----
  ISSUE_TILE(0, 0);
  ISSUE_MASK(mkA, 0);

  ROUND7(0, 1, mkA, mkB, 1);  // r0
  ROUND7(1, 0, mkB, mkA, 2);  // r1
  ROUND7(0, 1, mkA, mkB, 3);  // r2
  ROUND7(1, 0, mkB, mkA, 4);  // r3
  ROUND7(0, 1, mkA, mkB, 5);  // r4
  ROUND7(1, 0, mkB, mkA, 6);  // r5
  ROUND7(0, 1, mkA, mkB, 7);  // r6
  ROUND_LAST(1, mkB);         // r7

#undef ROUND_LAST
#undef ROUND7
#undef COMPUTE
#undef CONVERT
#undef ISSUE_MASK
#undef ISSUE_TILE
#undef ALOAD4
#undef SB

  // epilogue: C/D layout col=lane&15 (d), row=quad*4+reg (il); c = mt
#pragma unroll
  for (int mt = 0; mt < 3; ++mt) {
#pragma unroll
    for (int nt = 0; nt < 2; ++nt) {
      int d = w * 32 + nt * 16 + l15;
#pragma unroll
      for (int r = 0; r < 4; ++r) {
        int i = i0 + quad * 4 + r;
        out[(((size_t)b * N_ + i) * 3 + mt) * H_ + d] = acc[mt][nt][r];
      }
    }
  }
}

extern "C" void kernel_launch(void* const* d_in, const int* in_sizes, int n_in,
                              void* d_out, int out_size, void* d_ws,
                              size_t ws_size, hipStream_t stream) {
  const float* s = (const float*)d_in[0];
  const float* ev = (const float*)d_in[1];
  const float* mask = (const float*)d_in[2];
  const float* W1 = (const float*)d_in[3];
  const float* b1 = (const float*)d_in[4];
  float* out = (float*)d_out;
  // ws: h_t bf16 [B][128 d][512 n] = 4 MB
  unsigned short* h_t = (unsigned short*)d_ws;

  lin_ln_silu_kernel<<<dim3(N_ / 32, B_), 256, 0, stream>>>(s, W1, b1, h_t);
  cfconv_mfma_kernel<<<dim3(N_ / 16, B_), 256, 0, stream>>>(ev, mask, h_t, out);
}